// Round 2
// baseline (408.665 us; speedup 1.0000x reference)
//
#include <hip/hip_runtime.h>

// StreamNet K3 S1 halo conv: B=8, C=32, P=256, KB=2, R_MASK=1
// Padded input Xp[b][c][r][cc], r,cc in [0,258):
//   r < 2           -> bbuf[b][c][r][cc]           (bbuf is [B][C][2][258])
//   r>=2, cc < 2    -> rbuf[b][c][r-2][cc]         (rbuf is [B][C][256][2])
//   r>=2, cc>=2     -> (cc-2 == 255) ? 0 : x[b][c][r-2][cc-2]
// out[b][oc][y][x] = bias[oc] + sum_{ic,ky,kx} W[oc][ic][ky][kx] * Xp[b][ic][y+ky][x+kx]
//
// R2: phase-separated staging. Stage CHUNK=16 ic into LDS, then sweep compute.
// Rationale: R1 staged per-ic inside the reduction loop -> compiler pipelined
// global loads across acc[] live range -> acc spilled to scratch (VGPR_Count=24,
// VALUBusy=27%). Separating phases keeps compute-phase pressure at ~60 VGPRs.

constexpr int B    = 8;
constexpr int C    = 32;
constexpr int P    = 256;
constexpr int KB   = 2;
constexpr int TILE = 16;              // 16x16 output tile per block
constexpr int HT   = TILE + KB;       // 18 patch side
constexpr int SROW = 24;              // LDS row stride: rows 0..3 land at banks
                                      // +0/+24/+16/+8 -> uniform 2-way aliasing (free)
constexpr int CHUNK = 16;             // input channels per LDS stage

__global__ __launch_bounds__(256, 4) void streamnet_conv_kernel(
    const float* __restrict__ x,      // [B][C][P][P]
    const float* __restrict__ rbuf,   // [B][C][P][KB]
    const float* __restrict__ bbuf,   // [B][C][KB][P+KB]
    const float* __restrict__ W,      // [C][C][3][3]
    const float* __restrict__ bias,   // [C]
    float* __restrict__ out)          // [B][C][P][P]
{
    const int blk = blockIdx.x;            // b*256 + ty*16 + tx
    const int tx  = blk & 15;
    const int ty  = (blk >> 4) & 15;
    const int b   = blk >> 8;

    const int tid = threadIdx.x;
    const int lx  = tid & 15;              // output col within tile
    const int ly  = tid >> 4;              // output row within tile

    const int y0 = ty * TILE;
    const int x0 = tx * TILE;

    __shared__ float s[CHUNK][HT][SROW];   // 16*18*24*4 = 27648 B -> 5 blocks/CU by LDS

    float acc[C];
    #pragma unroll
    for (int oc = 0; oc < C; ++oc) acc[oc] = bias[oc];

    for (int icc = 0; icc < C / CHUNK; ++icc) {
        const int icBase = icc * CHUNK;
        __syncthreads();                   // prior chunk's LDS reads done

        // ---- stage CHUNK x 18 x 18 patch into LDS ----
        for (unsigned idx = tid; idx < CHUNK * HT * HT; idx += 256) {
            const unsigned ic  = idx / (HT * HT);
            const unsigned rem = idx - ic * (HT * HT);
            const unsigned rr  = rem / HT;
            const unsigned cc  = rem - rr * HT;
            const int r = y0 + (int)rr;    // Xp row
            const int c = x0 + (int)cc;    // Xp col
            const int gic = icBase + (int)ic;
            float v;
            if (r < KB) {
                v = bbuf[((size_t)(b * C + gic) * KB + r) * (P + KB) + c];
            } else {
                const int xr = r - KB;
                if (c < KB) {
                    v = rbuf[((size_t)(b * C + gic) * P + xr) * KB + c];
                } else {
                    const int xc = c - KB;
                    v = (xc == P - 1) ? 0.0f
                                      : x[((size_t)(b * C + gic) * P + xr) * P + xc];
                }
            }
            s[ic][rr][cc] = v;
        }
        __syncthreads();

        // ---- compute sweep: no global loads in here ----
        for (int i = 0; i < CHUNK; ++i) {
            float in[9];
            #pragma unroll
            for (int ky = 0; ky < 3; ++ky)
                #pragma unroll
                for (int kx = 0; kx < 3; ++kx)
                    in[ky * 3 + kx] = s[i][ly + ky][lx + kx];

            const int ic = icBase + i;
            #pragma unroll
            for (int oc = 0; oc < C; ++oc) {
                const float* w = W + (size_t)(oc * C + ic) * 9;   // wave-uniform -> s_load
                #pragma unroll
                for (int k = 0; k < 9; ++k)
                    acc[oc] = fmaf(w[k], in[k], acc[oc]);
            }
        }
    }

    // ---- epilogue: coalesced-by-16 stores ----
    const int y  = y0 + ly;
    const int xx = x0 + lx;
    #pragma unroll
    for (int oc = 0; oc < C; ++oc)
        out[((size_t)(b * C + oc) * P + y) * P + xx] = acc[oc];
}

extern "C" void kernel_launch(void* const* d_in, const int* in_sizes, int n_in,
                              void* d_out, int out_size, void* d_ws, size_t ws_size,
                              hipStream_t stream) {
    const float* x    = (const float*)d_in[0];
    const float* rbuf = (const float*)d_in[1];
    const float* bbuf = (const float*)d_in[2];
    const float* W    = (const float*)d_in[3];
    const float* bias = (const float*)d_in[4];
    float* out = (float*)d_out;

    const int grid = B * (P / TILE) * (P / TILE);   // 2048
    streamnet_conv_kernel<<<grid, 256, 0, stream>>>(x, rbuf, bbuf, W, bias, out);
}

// Round 3
// 242.898 us; speedup vs baseline: 1.6825x; 1.6825x over previous
//
#include <hip/hip_runtime.h>

// StreamNet K3 S1 halo conv: B=8, C=32, P=256, KB=2, R_MASK=1
// Padded input Xp[b][c][r][cc], r,cc in [0,258):
//   r < 2           -> bbuf[b][c][r][cc]           (bbuf is [B][C][2][258])
//   r>=2, cc < 2    -> rbuf[b][c][r-2][cc]         (rbuf is [B][C][256][2])
//   r>=2, cc>=2     -> (cc-2 == 255) ? 0 : x[b][c][r-2][cc-2]
//
// R3: weight amortization. R2 (1px x 32oc/thread) used each s_loaded weight
// once -> 36 s_load_dwordx8 per ic per wave on in-order lgkmcnt, starved at
// VGPR=44. Now: 1x4 pixel strip x 8 oc per thread -> each weight feeds 4 FMAs,
// ds_read_b128 input loads, dwordx4 stores. Wave = one oc-group (readfirstlane
// keeps weight addrs scalar). Grid 1024 x 2 tiles/block kills the tail.

constexpr int B    = 8;
constexpr int C    = 32;
constexpr int P    = 256;
constexpr int KB   = 2;
constexpr int TILE = 16;              // 16x16 output tile per block
constexpr int HT   = TILE + KB;       // 18 patch side
constexpr int SROW = 20;              // LDS row stride (words): rows hit banks
                                      // 0,20,8,28,16,4,24,12 mod 32 -> even spread
constexpr int CHUNK = 16;             // input channels per LDS stage

__global__ __launch_bounds__(256, 4) void streamnet_conv_kernel(
    const float* __restrict__ x,      // [B][C][P][P]
    const float* __restrict__ rbuf,   // [B][C][P][KB]
    const float* __restrict__ bbuf,   // [B][C][KB][P+KB]
    const float* __restrict__ W,      // [C][C][3][3]
    const float* __restrict__ bias,   // [C]
    float* __restrict__ out)          // [B][C][P][P]
{
    const int tid = threadIdx.x;
    // wave -> oc-group (8 oc); forced wave-uniform so W addressing is scalar
    const int ocg = __builtin_amdgcn_readfirstlane(tid >> 6);
    const int sid = tid & 63;              // lane: spatial strip id
    const int py  = sid >> 2;              // strip row 0..15
    const int px0 = (sid & 3) * 4;         // strip col base 0,4,8,12

    __shared__ float s[CHUNK][HT][SROW];   // 16*18*20*4 = 23040 B

    for (int t = 0; t < 2; ++t) {          // 2 tiles per block: balanced, no tail
        const int tile = blockIdx.x + t * 1024;
        const int tx = tile & 15;
        const int ty = (tile >> 4) & 15;
        const int b  = tile >> 8;
        const int y0 = ty * TILE;
        const int x0 = tx * TILE;

        float acc[8][4];
        #pragma unroll
        for (int o = 0; o < 8; ++o) {
            const float bv = bias[ocg * 8 + o];
            #pragma unroll
            for (int p = 0; p < 4; ++p) acc[o][p] = bv;
        }

        for (int icc = 0; icc < C / CHUNK; ++icc) {
            const int icBase = icc * CHUNK;
            __syncthreads();               // prior reads of s[] complete

            // ---- stage CHUNK x 18 x 18 patch into LDS (coalesced linear) ----
            for (unsigned idx = tid; idx < CHUNK * HT * HT; idx += 256) {
                const unsigned ic  = idx / (HT * HT);
                const unsigned rem = idx - ic * (HT * HT);
                const unsigned rr  = rem / HT;
                const unsigned cc  = rem - rr * HT;
                const int r = y0 + (int)rr;
                const int c = x0 + (int)cc;
                const int gic = icBase + (int)ic;
                float v;
                if (r < KB) {
                    v = bbuf[((size_t)(b * C + gic) * KB + r) * (P + KB) + c];
                } else {
                    const int xr = r - KB;
                    if (c < KB) {
                        v = rbuf[((size_t)(b * C + gic) * P + xr) * KB + c];
                    } else {
                        const int xc = c - KB;
                        v = (xc == P - 1) ? 0.0f
                                          : x[((size_t)(b * C + gic) * P + xr) * P + xc];
                    }
                }
                s[ic][rr][cc] = v;
            }
            __syncthreads();

            // ---- compute: 16 ic, each 8 oc x 9 taps x 4 px = 288 FMA ----
            for (int i = 0; i < CHUNK; ++i) {
                float in[3][6];
                #pragma unroll
                for (int r = 0; r < 3; ++r) {
                    const float4 q = *(const float4*)&s[i][py + r][px0];
                    const float2 h = *(const float2*)&s[i][py + r][px0 + 4];
                    in[r][0] = q.x; in[r][1] = q.y; in[r][2] = q.z; in[r][3] = q.w;
                    in[r][4] = h.x; in[r][5] = h.y;
                }
                const int ic = icBase + i;
                #pragma unroll
                for (int o = 0; o < 8; ++o) {
                    const float* w = W + (size_t)((ocg * 8 + o) * C + ic) * 9; // scalar
                    #pragma unroll
                    for (int ky = 0; ky < 3; ++ky)
                        #pragma unroll
                        for (int kx = 0; kx < 3; ++kx) {
                            const float wv = w[ky * 3 + kx];
                            #pragma unroll
                            for (int p = 0; p < 4; ++p)
                                acc[o][p] = fmaf(wv, in[ky][kx + p], acc[o][p]);
                        }
                }
            }
        }

        // ---- epilogue: dwordx4 stores ----
        #pragma unroll
        for (int o = 0; o < 8; ++o) {
            float* dst = &out[((size_t)(b * C + ocg * 8 + o) * P + (y0 + py)) * P + x0 + px0];
            *(float4*)dst = make_float4(acc[o][0], acc[o][1], acc[o][2], acc[o][3]);
        }
        __syncthreads();                   // tile 0 reads done before tile 1 staging
    }
}

extern "C" void kernel_launch(void* const* d_in, const int* in_sizes, int n_in,
                              void* d_out, int out_size, void* d_ws, size_t ws_size,
                              hipStream_t stream) {
    const float* x    = (const float*)d_in[0];
    const float* rbuf = (const float*)d_in[1];
    const float* bbuf = (const float*)d_in[2];
    const float* W    = (const float*)d_in[3];
    const float* bias = (const float*)d_in[4];
    float* out = (float*)d_out;

    streamnet_conv_kernel<<<1024, 256, 0, stream>>>(x, rbuf, bbuf, W, bias, out);
}

// Round 4
// 176.172 us; speedup vs baseline: 2.3197x; 1.3788x over previous
//
#include <hip/hip_runtime.h>
#include <cstdint>

// StreamNet K3 S1 halo conv, bf16 MFMA implicit-GEMM rewrite.
// Padded input Xp[b][c][r][cc], r,cc in [0,258):
//   r < 2           -> bbuf[b][c][r][cc]           (bbuf [B][C][2][258])
//   r>=2, cc < 2    -> rbuf[b][c][r-2][cc]         (rbuf [B][C][256][2])
//   r>=2, cc>=2     -> (cc-2 == 255) ? 0 : x[b][c][r-2][cc-2]
//
// R4: fp32 VALU floor is 61 us (no fp32 MFMA on CDNA4); threshold 9.3e-2
// permits bf16. Per 16x16 px tile x 32 oc: 9 taps x 2 oc-halves MFMAs
// (mfma_f32_16x16x32_bf16, K=32=C) = zero wasted MACs. New floor = HBM ~25us.
// LDS: Xs as ic-pair planes (staging writes stride-1 conflict-free; A-frag
// reads 4x ds_read_b32, PLANE=330 (2 mod 8) -> exactly 2 lanes/bank, free).
// W staged once/block -> B-frags live in registers across whole kernel.

constexpr int B  = 8;
constexpr int C  = 32;
constexpr int P  = 256;
constexpr int KB = 2;
constexpr int TILE = 16;
constexpr int HT   = TILE + KB;     // 18
constexpr int PLANE = 330;          // 18*18=324 + 6 pad; PLANE%8==2 spreads banks
constexpr int NPAIR = 16;           // ic pairs

typedef short bf16x8 __attribute__((ext_vector_type(8)));
typedef float f32x4  __attribute__((ext_vector_type(4)));

union Frag { uint32_t u[4]; bf16x8 v; };

static __device__ __forceinline__ uint32_t pk_bf16(float lo, float hi) {
    // RNE fp32->bf16 for both, pack into one dword (lo in low half)
    uint32_t a = __builtin_bit_cast(uint32_t, lo);
    uint32_t b2 = __builtin_bit_cast(uint32_t, hi);
    a  += 0x7FFFu + ((a  >> 16) & 1u);
    b2 += 0x7FFFu + ((b2 >> 16) & 1u);
    return (a >> 16) | (b2 & 0xFFFF0000u);
}

__global__ __launch_bounds__(256, 4) void conv_mfma(
    const float* __restrict__ x,      // [B][C][P][P]
    const float* __restrict__ rbuf,   // [B][C][P][KB]
    const float* __restrict__ bbuf,   // [B][C][KB][P+KB]
    const float* __restrict__ W,      // [C][C][3][3]
    const float* __restrict__ bias,   // [C]
    float* __restrict__ out)          // [B][C][P][P]
{
    const int tid = threadIdx.x;
    const int blk = blockIdx.x;
    const int tx = blk & 15, ty = (blk >> 4) & 15, b = blk >> 8;
    const int x0 = tx * TILE, y0 = ty * TILE;

    __shared__ uint32_t Xs[NPAIR * PLANE];   // 21120 B: bf16x2(ic=2m,2m+1) per pixel
    __shared__ uint32_t Ws[9 * 32 * 16];     // 18432 B: [tap][oc][icpair] bf16x2

    // ---- stage W: [oc][ic][3][3] fp32 -> Ws[t][oc][icpair] ----
    #pragma unroll
    for (int k = 0; k < 18; ++k) {           // 18*256 = 4608 dwords, exact
        const int u  = tid + k * 256;
        const int m  = u & 15;
        const int oc = (u >> 4) & 31;
        const int t  = u >> 9;               // 0..8
        const float lo = W[(oc * C + 2 * m) * 9 + t];
        const float hi = W[(oc * C + 2 * m + 1) * 9 + t];
        Ws[t * 512 + oc * 16 + m] = pk_bf16(lo, hi);
    }

    // ---- per-lane staging geometry (same for all ic): 2 pixel slots ----
    const float* xb  = x    + (size_t)(b * C) * P * P;        // plane 65536
    const float* rbb = rbuf + (size_t)(b * C) * P * KB;       // plane 512
    const float* bbb = bbuf + (size_t)(b * C) * KB * (P + KB);// plane 516

    const float* sbase[2]; int soff[2]; int spsz[2]; bool szero[2]; bool svalid[2];
    #pragma unroll
    for (int s = 0; s < 2; ++s) {
        const int pix = tid + 256 * s;
        svalid[s] = pix < HT * HT;
        const int pp = svalid[s] ? pix : 0;
        const int r = pp / HT, c = pp - r * HT;
        const int rg = y0 + r, cg = x0 + c;   // padded coords [0,258)
        if (rg < KB) {
            sbase[s] = bbb; soff[s] = rg * (P + KB) + cg; spsz[s] = KB * (P + KB); szero[s] = false;
        } else if (cg < KB) {
            sbase[s] = rbb; soff[s] = (rg - KB) * KB + cg; spsz[s] = P * KB; szero[s] = false;
        } else {
            sbase[s] = xb;  soff[s] = (rg - KB) * P + (cg - KB); spsz[s] = P * P;
            szero[s] = (cg == P + KB - 1);    // bypassed right edge -> 0
        }
    }

    // ---- stage X: loop ic pairs; writes are stride-1 dwords (conflict-free) ----
    for (int m = 0; m < NPAIR; ++m) {
        #pragma unroll
        for (int s = 0; s < 2; ++s) {
            if (svalid[s]) {
                const float* p = sbase[s] + (size_t)(2 * m) * spsz[s] + soff[s];
                const float lo = szero[s] ? 0.f : p[0];
                const float hi = szero[s] ? 0.f : p[spsz[s]];
                Xs[m * PLANE + tid + 256 * s] = pk_bf16(lo, hi);
            }
        }
    }
    __syncthreads();

    // ---- B fragments: held in registers for the whole kernel ----
    const int l   = tid & 63;
    const int q   = l >> 4;          // lane quad
    const int n16 = l & 15;
    const int w   = tid >> 6;        // wave id -> rows 4w..4w+3

    Frag Bf[9][2];
    #pragma unroll
    for (int t = 0; t < 9; ++t)
        #pragma unroll
        for (int oh = 0; oh < 2; ++oh) {
            const uint32_t* src = &Ws[t * 512 + (oh * 16 + n16) * 16 + q * 4];
            Bf[t][oh].u[0] = src[0]; Bf[t][oh].u[1] = src[1];
            Bf[t][oh].u[2] = src[2]; Bf[t][oh].u[3] = src[3];   // ds_read_b128
        }

    f32x4 acc[4][2];
    #pragma unroll
    for (int rr = 0; rr < 4; ++rr)
        #pragma unroll
        for (int oh = 0; oh < 2; ++oh)
            #pragma unroll
            for (int e = 0; e < 4; ++e) acc[rr][oh][e] = 0.f;

    // ---- 72 MFMAs per wave: D[m=px][n=oc] += A[px][ic] * B[ic][oc] per tap ----
    const int ybase = 4 * w;
    #pragma unroll
    for (int ky = 0; ky < 3; ++ky) {
        #pragma unroll
        for (int kx = 0; kx < 3; ++kx) {
            const int t = ky * 3 + kx;
            #pragma unroll
            for (int rr = 0; rr < 4; ++rr) {
                const int pidx = (ybase + rr + ky) * HT + kx + n16;  // A: m = n16
                Frag A;
                #pragma unroll
                for (int p = 0; p < 4; ++p)
                    A.u[p] = Xs[(4 * q + p) * PLANE + pidx];         // conflict-free
                acc[rr][0] = __builtin_amdgcn_mfma_f32_16x16x32_bf16(
                                 A.v, Bf[t][0].v, acc[rr][0], 0, 0, 0);
                acc[rr][1] = __builtin_amdgcn_mfma_f32_16x16x32_bf16(
                                 A.v, Bf[t][1].v, acc[rr][1], 0, 0, 0);
            }
        }
    }

    // ---- epilogue: D row = pixel 4q+reg -> float4 store, + bias ----
    #pragma unroll
    for (int oh = 0; oh < 2; ++oh) {
        const int oc = oh * 16 + n16;
        const float bv = bias[oc];
        #pragma unroll
        for (int rr = 0; rr < 4; ++rr) {
            const int y = y0 + ybase + rr;
            float4 v;
            v.x = acc[rr][oh][0] + bv;
            v.y = acc[rr][oh][1] + bv;
            v.z = acc[rr][oh][2] + bv;
            v.w = acc[rr][oh][3] + bv;
            *(float4*)&out[((size_t)(b * C + oc) * P + y) * P + x0 + 4 * q] = v;
        }
    }
}

extern "C" void kernel_launch(void* const* d_in, const int* in_sizes, int n_in,
                              void* d_out, int out_size, void* d_ws, size_t ws_size,
                              hipStream_t stream) {
    const float* x    = (const float*)d_in[0];
    const float* rbuf = (const float*)d_in[1];
    const float* bbuf = (const float*)d_in[2];
    const float* W    = (const float*)d_in[3];
    const float* bias = (const float*)d_in[4];
    float* out = (float*)d_out;

    conv_mfma<<<B * (P / TILE) * (P / TILE), 256, 0, stream>>>(x, rbuf, bbuf, W, bias, out);
}

// Round 6
// 148.000 us; speedup vs baseline: 2.7612x; 1.1904x over previous
//
#include <hip/hip_runtime.h>
#include <cstdint>

// StreamNet K3 S1 halo conv, bf16 MFMA implicit-GEMM, pipelined.
// Padded input Xp[b][c][r][cc], r,cc in [0,258):
//   r < 2           -> bbuf[b][c][r][cc]           (bbuf [B][C][2][258])
//   r>=2, cc < 2    -> rbuf[b][c][r-2][cc]         (rbuf [B][C][256][2])
//   r>=2, cc>=2     -> (cc-2 == 255) ? 0 : x[b][c][r-2][cc-2]
//
// R6 = R5 with the halo-source bug fixed. R5 hardcoded top-halo:=bbuf and
// left-halo:=rbuf, valid only for ty==0 / tx==0 tiles; interior tiles take
// their halos from x rows y0-2..y0-1 / cols x0-2..x0-1. Restored R4's generic
// per-cell source resolution (sel/off/zero precomputed per lane, base-pointer
// table per batch). Vectorized staging + double-buffer pipeline unchanged.

constexpr int B  = 8;
constexpr int C  = 32;
constexpr int P  = 256;
constexpr int KB = 2;
constexpr int TILE = 16;
constexpr int RS = 20;            // LDS row stride (dwords)
constexpr int PL = 364;           // plane stride (dwords); 364%32=12 -> A reads 2-way, free
constexpr int XSZ = 16 * PL;      // dwords per buffer

typedef short bf16x8 __attribute__((ext_vector_type(8)));
typedef float f32x4  __attribute__((ext_vector_type(4)));
union Frag { uint32_t u[4]; bf16x8 v; };

static __device__ __forceinline__ uint32_t pk_bf16(float lo, float hi) {
    uint32_t a  = __builtin_bit_cast(uint32_t, lo);
    uint32_t b2 = __builtin_bit_cast(uint32_t, hi);
    a  += 0x7FFFu + ((a  >> 16) & 1u);
    b2 += 0x7FFFu + ((b2 >> 16) & 1u);
    return (a >> 16) | (b2 & 0xFFFF0000u);
}

struct Staged {                    // in-flight staging: 4 ic-pairs per wave
    float4 ilo[4], ihi[4];         // interior 16x16
    float  tlo[4], thi[4];         // top halo  (lanes < 36): patch rows 0..1
    float  llo[4], lhi[4];         // left halo (lanes < 32): patch rows 2..17, cols 0..1
};

__global__ __launch_bounds__(256, 2) void conv_mfma(
    const float* __restrict__ x,      // [B][C][P][P]
    const float* __restrict__ rbuf,   // [B][C][P][KB]
    const float* __restrict__ bbuf,   // [B][C][KB][P+KB]
    const float* __restrict__ W,      // [C][C][3][3]
    const float* __restrict__ bias,   // [C]
    float* __restrict__ out)          // [B][C][P][P]
{
    const int tid  = threadIdx.x;
    const int lane = tid & 63;
    const int w    = tid >> 6;        // wave 0..3
    const int q    = lane >> 4;
    const int n16  = lane & 15;

    const int blk = blockIdx.x;       // 0..511
    const int tx = blk & 15, ty = (blk >> 4) & 15, b0 = blk >> 8;   // b0 in {0,1}
    const int x0 = tx * TILE, y0 = ty * TILE;

    __shared__ uint32_t Xs[2 * XSZ];  // 46592 B (double buffer)
    __shared__ uint32_t Ws[9 * 512];  // 18432 B   total 65024 B

    // ---- W stage, once per block ----
    #pragma unroll
    for (int k = 0; k < 18; ++k) {
        const int u  = tid + k * 256;
        const int m  = u & 15;
        const int oc = (u >> 4) & 31;
        const int t  = u >> 9;
        const float lo = W[(oc * C + 2 * m) * 9 + t];
        const float hi = W[(oc * C + 2 * m + 1) * 9 + t];
        Ws[t * 512 + oc * 16 + m] = pk_bf16(lo, hi);
    }

    // ---- staging lane geometry (tile-invariant within block) ----
    const int irow  = lane >> 2;                 // 0..15
    const int icol4 = (lane & 3) * 4;            // 0,4,8,12
    const bool zc   = (x0 == P - TILE) && ((lane & 3) == 3);  // xc==255 in .w

    // halo cells: generic source resolution (sel: 0=x, 1=rbuf, 2=bbuf)
    const int t_r = lane >= 18 ? 1 : 0;          // top halo patch row
    const int t_c = lane - 18 * t_r;             // top halo patch col 0..17
    int t_sel = 0, t_off = 0; bool t_zero = false;
    {
        const int rg = y0 + t_r, cg = x0 + t_c;
        if (rg < KB)      { t_sel = 2; t_off = rg * (P + KB) + cg; }
        else if (cg < KB) { t_sel = 1; t_off = (rg - KB) * KB + cg; }
        else              { t_sel = 0; t_off = (rg - KB) * P + (cg - KB);
                            t_zero = (cg == P + KB - 1); }
    }
    const int l_r = lane >> 1;                   // 0..15 -> patch row l_r+2
    const int l_c = lane & 1;                    // patch col 0..1
    int l_sel = 0, l_off = 0;
    {
        const int rg = y0 + KB + l_r, cg = x0 + l_c;   // rg >= 2 always
        if (cg < KB) { l_sel = 1; l_off = (rg - KB) * KB + cg; }
        else         { l_sel = 0; l_off = (rg - KB) * P + (cg - KB); }  // never col 255
    }

    auto stage_load = [&](int bt, Staged& S) {
        const float* xb = x    + (size_t)bt * C * P * P;
        const float* rb = rbuf + (size_t)bt * C * P * KB;
        const float* bb = bbuf + (size_t)bt * C * KB * (P + KB);
        const float* basep[3] = { xb, rb, bb };
        const int    psz[3]   = { P * P, P * KB, KB * (P + KB) };
        #pragma unroll
        for (int k2 = 0; k2 < 4; ++k2) {
            const int m = 4 * k2 + w;            // ic-pair owned by this wave
            const float* pi = xb + (2 * m) * (P * P) + (y0 + irow) * P + x0 + icol4;
            S.ilo[k2] = *(const float4*)pi;
            S.ihi[k2] = *(const float4*)(pi + P * P);
            if (lane < 36) {
                const float* pt = basep[t_sel] + (size_t)(2 * m) * psz[t_sel] + t_off;
                S.tlo[k2] = t_zero ? 0.f : pt[0];
                S.thi[k2] = t_zero ? 0.f : pt[psz[t_sel]];
            }
            if (lane < 32) {
                const float* pl = basep[l_sel] + (size_t)(2 * m) * psz[l_sel] + l_off;
                S.llo[k2] = pl[0];
                S.lhi[k2] = pl[psz[l_sel]];
            }
        }
    };

    auto stage_store = [&](uint32_t* Xb, Staged& S) {
        #pragma unroll
        for (int k2 = 0; k2 < 4; ++k2) {
            const int m = 4 * k2 + w;
            float4 lo = S.ilo[k2], hi = S.ihi[k2];
            if (zc) { lo.w = 0.f; hi.w = 0.f; }
            uint32_t* dst = Xb + m * PL + (irow + KB) * RS + (icol4 + KB);
            dst[0] = pk_bf16(lo.x, hi.x);
            dst[1] = pk_bf16(lo.y, hi.y);
            dst[2] = pk_bf16(lo.z, hi.z);
            dst[3] = pk_bf16(lo.w, hi.w);
            if (lane < 36) Xb[m * PL + t_r * RS + t_c]         = pk_bf16(S.tlo[k2], S.thi[k2]);
            if (lane < 32) Xb[m * PL + (l_r + KB) * RS + l_c]  = pk_bf16(S.llo[k2], S.lhi[k2]);
        }
    };

    // ---- prologue: stage tile 0 into buffer 0 ----
    Staged S;
    stage_load(b0, S);
    stage_store(Xs, S);
    __syncthreads();

    // ---- B fragments: registers for the whole kernel ----
    Frag Bf[9][2];
    #pragma unroll
    for (int t = 0; t < 9; ++t)
        #pragma unroll
        for (int oh = 0; oh < 2; ++oh) {
            const uint32_t* src = &Ws[t * 512 + (oh * 16 + n16) * 16 + q * 4];
            Bf[t][oh].u[0] = src[0]; Bf[t][oh].u[1] = src[1];
            Bf[t][oh].u[2] = src[2]; Bf[t][oh].u[3] = src[3];
        }
    const float bv0 = bias[n16];
    const float bv1 = bias[16 + n16];

    // ---- tile loop: tiles (b0+2t, ty, tx), double-buffered ----
    for (int t = 0; t < 4; ++t) {
        const uint32_t* Xc = Xs + (t & 1) * XSZ;
        const int bt = b0 + 2 * t;

        if (t < 3) stage_load(b0 + 2 * (t + 1), S);   // issue before MFMA sweep

        f32x4 acc[4][2];
        #pragma unroll
        for (int rr = 0; rr < 4; ++rr)
            #pragma unroll
            for (int oh = 0; oh < 2; ++oh)
                #pragma unroll
                for (int e = 0; e < 4; ++e) acc[rr][oh][e] = 0.f;

        // A-frags deduped: patch row 4w+dr serves all (rr,ky) with rr+ky==dr
        #pragma unroll
        for (int dr = 0; dr < 6; ++dr) {
            Frag A[3];
            const uint32_t* ap = Xc + (4 * q) * PL + (4 * w + dr) * RS + n16;
            #pragma unroll
            for (int kx = 0; kx < 3; ++kx)
                #pragma unroll
                for (int p = 0; p < 4; ++p)
                    A[kx].u[p] = ap[p * PL + kx];
            #pragma unroll
            for (int ky = 0; ky < 3; ++ky) {
                const int rr = dr - ky;
                if (rr >= 0 && rr < 4) {
                    #pragma unroll
                    for (int kx = 0; kx < 3; ++kx) {
                        acc[rr][0] = __builtin_amdgcn_mfma_f32_16x16x32_bf16(
                                         A[kx].v, Bf[ky * 3 + kx][0].v, acc[rr][0], 0, 0, 0);
                        acc[rr][1] = __builtin_amdgcn_mfma_f32_16x16x32_bf16(
                                         A[kx].v, Bf[ky * 3 + kx][1].v, acc[rr][1], 0, 0, 0);
                    }
                }
            }
        }

        // ---- epilogue: D[m=px 4q+e][n=oc n16] -> float4 stores ----
        #pragma unroll
        for (int oh = 0; oh < 2; ++oh) {
            const int oc = oh * 16 + n16;
            const float bv = oh ? bv1 : bv0;
            #pragma unroll
            for (int rr = 0; rr < 4; ++rr) {
                float4 v;
                v.x = acc[rr][oh][0] + bv;
                v.y = acc[rr][oh][1] + bv;
                v.z = acc[rr][oh][2] + bv;
                v.w = acc[rr][oh][3] + bv;
                *(float4*)&out[((size_t)(bt * C + oc) * P + (y0 + 4 * w + rr)) * P + x0 + 4 * q] = v;
            }
        }

        if (t < 3) stage_store(Xs + ((t + 1) & 1) * XSZ, S);
        __syncthreads();
    }
}

extern "C" void kernel_launch(void* const* d_in, const int* in_sizes, int n_in,
                              void* d_out, int out_size, void* d_ws, size_t ws_size,
                              hipStream_t stream) {
    const float* x    = (const float*)d_in[0];
    const float* rbuf = (const float*)d_in[1];
    const float* bbuf = (const float*)d_in[2];
    const float* W    = (const float*)d_in[3];
    const float* bias = (const float*)d_in[4];
    float* out = (float*)d_out;

    conv_mfma<<<512, 256, 0, stream>>>(x, rbuf, bbuf, W, bias, out);
}